// Round 7
// baseline (769.061 us; speedup 1.0000x reference)
//
#include <hip/hip_runtime.h>

// ---------------------------------------------------------------------------
// Fused equivariant FFN, bf16 MFMA (16x16x32), fp32 accumulate.
// Round 7 = Round 5 (334us) + three surgical changes:
//  1) __launch_bounds__(512,6): 3 blocks/CU (LDS 52.7KB x3 = 158KB fits).
//  2) Wave balance: B1-GEMM2 on all 8 waves, B2-GEMM2 on 4 waves, B2-GEMM1
//     mapped so each wave uses exactly one prefetched W2 fragment.
//  3) Less serialization: x2T staging overlapped with B1-GEMM2(mm=2);
//     ubuf2 double-buffered so B2-GEMM1(mm+1) overlaps B2-GEMM2(mm).
// Weight fragments stay prefetched behind barriers and reused (R6 lesson).
// ---------------------------------------------------------------------------

typedef __attribute__((ext_vector_type(8))) short short8;   // 8 bf16 = 4 VGPRs
typedef __attribute__((ext_vector_type(4))) float f32x4;

#define INV_M0f 0.08838834764831845f   // 1/sqrt(128)
#define INV_M1f 0.125f                 // 1/sqrt(64)
#define INV_M2f 0.17677669529663687f   // 1/sqrt(32)
#define INV_H0f 0.05103103630798288f   // 1/sqrt(384)
#define INV_H1f 0.07216878364870323f   // 1/sqrt(192)
#define INV_H2f 0.10206207261596577f   // 1/sqrt(96)

// packed bf16 weight offsets inside d_ws (units: shorts), pre-scaled by INV_*
#define OFF_W0T 0         // [672][128]  (W0s|W0g)^T * INV_M0
#define OFF_W1T 86016     // [192][64]   W1^T * INV_M1
#define OFF_W2T 98304     // [96][32]    W2^T * INV_M2
#define OFF_V0T 101376    // [128][384]  V0^T * INV_H0
#define OFF_V1T 150528    // [64][192]   V1^T * INV_H1
#define OFF_V2T 162816    // [32][96]    V2^T * INV_H2
#define WP_TOTAL 165888

__device__ __forceinline__ short f2bf_rne(float f) {        // prep only
    union { float f; unsigned u; } v; v.f = f;
    unsigned r = v.u + 0x7FFFu + ((v.u >> 16) & 1u);
    return (short)(r >> 16);
}
// 1-VALU bf16 convert (RNE) for the hot kernel
__device__ __forceinline__ short f2bf_fast(float f) {
    unsigned r;
    asm("v_cvt_pk_bf16_f32 %0, %1, %1" : "=v"(r) : "v"(f));
    return (short)r;
}
__device__ __forceinline__ float bf2f(short s) {
    union { unsigned u; float f; } v; v.u = ((unsigned)(unsigned short)s) << 16;
    return v.f;
}

__global__ void prep_weights(const float* __restrict__ W0s, const float* __restrict__ W0g,
                             const float* __restrict__ W1,  const float* __restrict__ W2,
                             const float* __restrict__ V0,  const float* __restrict__ V1,
                             const float* __restrict__ V2,  short* __restrict__ ws)
{
    int i = blockIdx.x * 256 + threadIdx.x;
    if (i < 86016) {                    // W0T [672][128]
        int j = i >> 7, k = i & 127;
        float v = (j < 384) ? W0s[k * 384 + j] : W0g[k * 288 + (j - 384)];
        ws[i] = f2bf_rne(v * INV_M0f);
    } else if (i < 98304) {             // W1T [192][64]
        int e = i - 86016; int w = e >> 6, u = e & 63;
        ws[i] = f2bf_rne(W1[u * 192 + w] * INV_M1f);
    } else if (i < 101376) {            // W2T [96][32]
        int e = i - 98304; int w = e >> 5, u = e & 31;
        ws[i] = f2bf_rne(W2[u * 96 + w] * INV_M2f);
    } else if (i < 150528) {            // V0T [128][384]
        int e = i - 101376; int j = e / 384, w = e % 384;
        ws[i] = f2bf_rne(V0[w * 128 + j] * INV_H0f);
    } else if (i < 162816) {            // V1T [64][192]
        int e = i - 150528; int j = e / 192, w = e % 192;
        ws[i] = f2bf_rne(V1[w * 64 + j] * INV_H1f);
    } else if (i < WP_TOTAL) {          // V2T [32][96]
        int e = i - 162816; int j = e / 96, w = e % 96;
        ws[i] = f2bf_rne(V2[w * 32 + j] * INV_H2f);
    }
}

// ---- LDS layout (shorts), 32 nodes, total 26368 shorts = 52736 B ----
// x0s   @     0 : [32][136] = 4352   (start -> end Phase A)
// sbuf  @  4352 : [32][392] = 12544  (Phase A -> Phase D)    [4352,16896)
// gbuf  @ 16896 : [32][296] = 9472   (Phase A -> end)        [16896,26368)
// x1T   @     0 : [3][32][72] = 6912 (after D; overlays dead x0s+sbuf head)
// ubuf1 @  6912 : [32][200] = 6400   (B1; overlays dead sbuf) [6912,13312)
// x2T   @     0 : [5][32][40] = 6400 (staged during B1-G2(2); dead x1T)
// ubuf2A@  6400 : [32][104] = 3328   (B2 double-buffer)       [6400, 9728)
// ubuf2B@  9728 : [32][104] = 3328                            [9728,13056)
#define X0_STRIDE 136
#define SB_OFF 4352
#define SB_STRIDE 392
#define GB_OFF 16896
#define GB_STRIDE 296
#define UB1_OFF 6912
#define UB1_STRIDE 200
#define UB2A_OFF 6400
#define UB2B_OFF 9728
#define UB2_STRIDE 104
#define LDS_SHORTS 26368

#define MFMA(a, b, c) __builtin_amdgcn_mfma_f32_16x16x32_bf16((a), (b), (c), 0, 0, 0)

__global__ __launch_bounds__(512, 6) void ffn_main(
    const float* __restrict__ X, const float* __restrict__ Y,
    const float* __restrict__ bs, const float* __restrict__ bg, const float* __restrict__ bo,
    const short* __restrict__ WP, float* __restrict__ out)
{
    __shared__ short lds[LDS_SHORTS];
    short* x0s   = lds;
    short* sbuf  = lds + SB_OFF;
    short* gbuf  = lds + GB_OFF;
    short* x1T   = lds;
    short* x2T   = lds;
    short* ubuf1 = lds + UB1_OFF;
    short* ubuf2A = lds + UB2A_OFF;
    short* ubuf2B = lds + UB2B_OFF;

    const int tid  = threadIdx.x;
    const int wid  = tid >> 6;     // wave 0..7
    const int lane = tid & 63;
    const int m    = lane & 15;    // A-row / B-col / D-col index
    const int bq   = lane >> 4;    // k-block; D row-group
    const int n0   = blockIdx.x * 32;

    // ---- prefetch first Phase-A weight tile (overlaps x0 staging) ----
    short8 w0c[4];
    float bias_c;
    {
        const short* w = WP + OFF_W0T + (wid * 16 + m) * 128 + bq * 8;
        #pragma unroll
        for (int k = 0; k < 4; ++k) w0c[k] = *(const short8*)(w + k * 32);
        bias_c = bs[wid * 16 + m];          // first jt = wid < 24 -> always bs
    }

    // ---- stage x0 (32 nodes x 128 cols) -> LDS bf16, coalesced ----
    {
        const int node = tid >> 4, c16 = tid & 15;
        const float* xp = X + (size_t)(n0 + node) * 480 + c16 * 8;
        float4 f0 = *(const float4*)xp;
        float4 f1 = *(const float4*)(xp + 4);
        short8 a;
        a[0]=f2bf_fast(f0.x); a[1]=f2bf_fast(f0.y); a[2]=f2bf_fast(f0.z); a[3]=f2bf_fast(f0.w);
        a[4]=f2bf_fast(f1.x); a[5]=f2bf_fast(f1.y); a[6]=f2bf_fast(f1.z); a[7]=f2bf_fast(f1.w);
        *(short8*)(x0s + node * X0_STRIDE + c16 * 8) = a;
    }

    // y for the 8 rows this lane touches: rows t*16 + bq*4 + r
    float yv[2][4];
    #pragma unroll
    for (int t = 0; t < 2; ++t)
        #pragma unroll
        for (int r = 0; r < 4; ++r)
            yv[t][r] = Y[n0 + t * 16 + bq * 4 + r];

    __syncthreads();                                        // [b1]

    // x0 A-fragments, both row-tiles
    short8 a0[2][4];
    #pragma unroll
    for (int t = 0; t < 2; ++t)
        #pragma unroll
        for (int k = 0; k < 4; ++k)
            a0[t][k] = *(const short8*)(x0s + (t * 16 + m) * X0_STRIDE + k * 32 + bq * 8);

    // ---- Phase A: pre(32x672) = x0 @ W0T^T ; s -> sbuf, g -> gbuf ----
    #pragma unroll 1
    for (int i = 0; i < 6; ++i) {
        const int jt = wid + i * 8;
        if (jt >= 42) break;
        const int jn = jt + 8;
        short8 w0n[4];
        float bias_n = 0.f;
        if (jn < 42) {
            const short* w = WP + OFF_W0T + (jn * 16 + m) * 128 + bq * 8;
            #pragma unroll
            for (int k = 0; k < 4; ++k) w0n[k] = *(const short8*)(w + k * 32);
            bias_n = (jn < 24) ? bs[jn * 16 + m] : bg[(jn - 24) * 16 + m];
        }
        f32x4 acc0 = {0.f,0.f,0.f,0.f}, acc1 = {0.f,0.f,0.f,0.f};
        #pragma unroll
        for (int k = 0; k < 4; ++k) {
            acc0 = MFMA(a0[0][k], w0c[k], acc0);
            acc1 = MFMA(a0[1][k], w0c[k], acc1);
        }
        if (jt < 24) {          // silu -> sbuf
            #pragma unroll
            for (int t = 0; t < 2; ++t) {
                f32x4 acc = t ? acc1 : acc0;
                #pragma unroll
                for (int r = 0; r < 4; ++r) {
                    float val = fmaf(acc[r], yv[t][r], bias_c);
                    float e   = __expf(-val);
                    float sv  = val * __builtin_amdgcn_rcpf(1.f + e);
                    sbuf[(t * 16 + bq * 4 + r) * SB_STRIDE + jt * 16 + m] = f2bf_fast(sv);
                }
            }
        } else {                // sigmoid -> gbuf
            #pragma unroll
            for (int t = 0; t < 2; ++t) {
                f32x4 acc = t ? acc1 : acc0;
                #pragma unroll
                for (int r = 0; r < 4; ++r) {
                    float val = fmaf(acc[r], yv[t][r], bias_c);
                    float e   = __expf(-val);
                    float sg  = __builtin_amdgcn_rcpf(1.f + e);
                    gbuf[(t * 16 + bq * 4 + r) * GB_STRIDE + (jt - 24) * 16 + m] = f2bf_fast(sg);
                }
            }
        }
        #pragma unroll
        for (int k = 0; k < 4; ++k) w0c[k] = w0n[k];
        bias_c = bias_n;
    }

    // ---- prefetch Phase-D weights (V0T) + bias before the barrier ----
    short8 v0f[12];
    {
        const short* v = WP + OFF_V0T + (wid * 16 + m) * 384 + bq * 8;
        #pragma unroll
        for (int k = 0; k < 12; ++k) v0f[k] = *(const short8*)(v + k * 32);
    }
    const float bo_r = bo[wid * 16 + m];
    __syncthreads();                                        // [b2]

    // ---- Phase D: o0(32x128) = s @ V0 ; 1 j-tile per wave, dense stores ----
    {
        f32x4 accD0 = {0.f,0.f,0.f,0.f}, accD1 = {0.f,0.f,0.f,0.f};
        #pragma unroll
        for (int k = 0; k < 12; ++k) {
            short8 sa0 = *(const short8*)(sbuf + m * SB_STRIDE + k * 32 + bq * 8);
            short8 sa1 = *(const short8*)(sbuf + (16 + m) * SB_STRIDE + k * 32 + bq * 8);
            accD0 = MFMA(sa0, v0f[k], accD0);
            accD1 = MFMA(sa1, v0f[k], accD1);
        }
        #pragma unroll
        for (int t = 0; t < 2; ++t) {
            f32x4 acc = t ? accD1 : accD0;
            #pragma unroll
            for (int r = 0; r < 4; ++r)
                out[(size_t)(n0 + t * 16 + bq * 4 + r) * 480 + wid * 16 + m] =
                    fmaf(acc[r], yv[t][r], bo_r);
        }
    }

    // ---- prefetch B1/B2 weights while D's sbuf reads drain ----
    // B1-GEMM1: waves get j-pairs jt = wid (+8)
    short8 w1f[2][2];
    #pragma unroll
    for (int jj = 0; jj < 2; ++jj) {
        const int jt = wid + jj * 8;
        if (jt < 12) {
            const short* w = WP + OFF_W1T + (jt * 16 + m) * 64 + bq * 8;
            w1f[jj][0] = *(const short8*)(w);
            w1f[jj][1] = *(const short8*)(w + 32);
        }
    }
    // B1-GEMM2: all 8 waves, unit (ct1 = wid&3, t1 = wid>>2)
    const int ct1 = wid & 3, t1 = wid >> 2;
    short8 v1f[6];
    {
        const short* v = WP + OFF_V1T + (ct1 * 16 + m) * 192 + bq * 8;
        #pragma unroll
        for (int k = 0; k < 6; ++k) v1f[k] = *(const short8*)(v + k * 32);
    }
    // B2-GEMM1: each wave exactly one W2 j-tile:
    //   wid>=4: jt2 = wid-4, row-tiles {0,1}; wid<4: jt2 = 4+(wid>>1), rt = wid&1
    const int jt2 = (wid >= 4) ? (wid - 4) : (4 + (wid >> 1));
    const short8 w2f = *(const short8*)(WP + OFF_W2T + (jt2 * 16 + m) * 32 + bq * 8);
    // B2-GEMM2: waves 0..3, unit (ct2 = wid&1, t2 = wid>>1)
    const int ct2 = wid & 1, t2 = wid >> 1;
    short8 v2f[3];
    if (wid < 4) {
        const short* v = WP + OFF_V2T + (ct2 * 16 + m) * 96 + bq * 8;
        #pragma unroll
        for (int k = 0; k < 3; ++k) v2f[k] = *(const short8*)(v + k * 32);
    }
    // per-lane y rows with wave-static selects (no dynamic reg indexing)
    float y_t1[4], y_t2[4];
    #pragma unroll
    for (int r = 0; r < 4; ++r) {
        y_t1[r] = t1 ? yv[1][r] : yv[0][r];
        y_t2[r] = t2 ? yv[1][r] : yv[0][r];
    }
    __syncthreads();   // [b3] sbuf reads done; x1T region may be written

    // ---- stage x1 as [3][32][72]: plane mm, row node ----
    {
        const int node = tid >> 4, c16 = tid & 15;
        const float* xp = X + (size_t)(n0 + node) * 480 + 128 + c16 * 12;
        float4 fa = *(const float4*)xp;
        float4 fb = *(const float4*)(xp + 4);
        float4 fc = *(const float4*)(xp + 8);
        float vals[12] = {fa.x,fa.y,fa.z,fa.w, fb.x,fb.y,fb.z,fb.w, fc.x,fc.y,fc.z,fc.w};
        #pragma unroll
        for (int c = 0; c < 12; ++c) {
            const int u   = c16 * 4 + c / 3;    // static per c
            const int mmv = c % 3;
            x1T[mmv * 2304 + node * 72 + u] = f2bf_fast(vals[c]);
        }
    }
    __syncthreads();                                        // [b4]

    // ---- Phase B1: per mm: GEMM1 (gate) -> ubuf1 ; GEMM2 -> registers ----
    f32x4 o1f[3];
    #pragma unroll
    for (int mm = 0; mm < 3; ++mm) {
        // GEMM1: v1_mm(32x192) = x1_mm @ W1 ; j-pairs over waves (prefetched w1f)
        #pragma unroll
        for (int jj = 0; jj < 2; ++jj) {
            const int jt = wid + jj * 8;
            if (jt < 12) {
                f32x4 accA = {0.f,0.f,0.f,0.f}, accB = {0.f,0.f,0.f,0.f};
                short8 a00 = *(const short8*)(x1T + mm * 2304 + m * 72 + bq * 8);
                short8 a01 = *(const short8*)(x1T + mm * 2304 + m * 72 + 32 + bq * 8);
                short8 a10 = *(const short8*)(x1T + mm * 2304 + (16 + m) * 72 + bq * 8);
                short8 a11 = *(const short8*)(x1T + mm * 2304 + (16 + m) * 72 + 32 + bq * 8);
                accA = MFMA(a00, w1f[jj][0], accA);
                accA = MFMA(a01, w1f[jj][1], accA);
                accB = MFMA(a10, w1f[jj][0], accB);
                accB = MFMA(a11, w1f[jj][1], accB);
                #pragma unroll
                for (int t = 0; t < 2; ++t) {
                    f32x4 acc = t ? accB : accA;
                    #pragma unroll
                    for (int r = 0; r < 4; ++r) {
                        const int node = t * 16 + bq * 4 + r;
                        float gv = bf2f(gbuf[node * GB_STRIDE + jt * 16 + m]);
                        ubuf1[node * UB1_STRIDE + jt * 16 + m] =
                            f2bf_fast(acc[r] * yv[t][r] * gv);
                    }
                }
            }
        }
        __syncthreads();                                    // ubuf1 ready
        // x2 global loads issued early (mm==2 only), hidden under GEMM2 MFMAs
        float xv2[10];
        if (mm == 2) {
            const int node2 = tid >> 4, c16 = tid & 15;
            const float* xp2 = X + (size_t)(n0 + node2) * 480 + 320 + c16 * 10;
            #pragma unroll
            for (int p = 0; p < 5; ++p) {
                float2 f = *(const float2*)(xp2 + p * 2);
                xv2[p * 2] = f.x; xv2[p * 2 + 1] = f.y;
            }
        }
        // GEMM2: o1_mm(32x64) = u @ V1 ; all 8 waves, unit (ct1,t1)
        {
            f32x4 acc = {0.f,0.f,0.f,0.f};
            #pragma unroll
            for (int k = 0; k < 6; ++k) {
                short8 a = *(const short8*)(ubuf1 + (t1 * 16 + m) * UB1_STRIDE + k * 32 + bq * 8);
                acc = MFMA(a, v1f[k], acc);
            }
            o1f[mm] = acc;
        }
        // x2T staging writes (mm==2): x1T fully dead after this mm's GEMM1
        if (mm == 2) {
            const int node2 = tid >> 4, c16 = tid & 15;
            #pragma unroll
            for (int c = 0; c < 10; ++c) {
                const int u   = c16 * 2 + c / 5;    // static per c
                const int mmv = c % 5;
                x2T[(mmv * 1280) + node2 * 40 + u] = f2bf_fast(xv2[c]);
            }
        }
        __syncthreads();   // protects ubuf1 rewrite (mm<2) / x2T+ubuf2A (mm==2)
    }
    // dense o1 stores: 12 B contiguous per (node, j)
    #pragma unroll
    for (int r = 0; r < 4; ++r) {
        const float yy = y_t1[r];
        float* pp = out + (size_t)(n0 + t1 * 16 + bq * 4 + r) * 480 + 128 + (ct1 * 16 + m) * 3;
        pp[0] = o1f[0][r] * yy; pp[1] = o1f[1][r] * yy; pp[2] = o1f[2][r] * yy;
    }

    // ---- Phase B2: double-buffered ubuf2; G1(mm+1) overlaps G2(mm) ----
    // B2-GEMM1 for plane mmv into dst
    auto b2_g1 = [&](int mmv, short* dst) {
        #pragma unroll
        for (int q = 0; q < 2; ++q) {
            if (q == 0 || wid >= 4) {
                const int rt = (wid >= 4) ? q : (wid & 1);
                short8 a = *(const short8*)(x2T + mmv * 1280 + (rt * 16 + m) * 40 + bq * 8);
                f32x4 z = {0.f,0.f,0.f,0.f};
                f32x4 acc = MFMA(a, w2f, z);
                #pragma unroll
                for (int r = 0; r < 4; ++r) {
                    const int node = rt * 16 + bq * 4 + r;
                    const float yy = rt ? yv[1][r] : yv[0][r];
                    float gv = bf2f(gbuf[node * GB_STRIDE + 192 + jt2 * 16 + m]);
                    dst[node * UB2_STRIDE + jt2 * 16 + m] = f2bf_fast(acc[r] * yy * gv);
                }
            }
        }
    };

    b2_g1(0, ubuf2A);
    __syncthreads();                                        // bufA ready

    f32x4 o2f[5];
    #pragma unroll
    for (int mm = 0; mm < 5; ++mm) {
        if (mm < 4) b2_g1(mm + 1, (mm & 1) ? ubuf2A : ubuf2B);  // buf[(mm+1)&1]
        if (wid < 4) {                  // GEMM2 from buf[mm&1]
            const short* src = (mm & 1) ? ubuf2B : ubuf2A;
            f32x4 acc = {0.f,0.f,0.f,0.f};
            #pragma unroll
            for (int k = 0; k < 3; ++k) {
                short8 a = *(const short8*)(src + (t2 * 16 + m) * UB2_STRIDE + k * 32 + bq * 8);
                acc = MFMA(a, v2f[k], acc);
            }
            o2f[mm] = acc;
        }
        if (mm < 4) __syncthreads();
    }
    // dense o2 stores: 20 B contiguous per (node, j)
    if (wid < 4) {
        #pragma unroll
        for (int r = 0; r < 4; ++r) {
            const float yy = y_t2[r];
            float* pp = out + (size_t)(n0 + t2 * 16 + bq * 4 + r) * 480 + 320 + (ct2 * 16 + m) * 5;
            pp[0] = o2f[0][r] * yy; pp[1] = o2f[1][r] * yy; pp[2] = o2f[2][r] * yy;
            pp[3] = o2f[3][r] * yy; pp[4] = o2f[4][r] * yy;
        }
    }
}

extern "C" void kernel_launch(void* const* d_in, const int* in_sizes, int n_in,
                              void* d_out, int out_size, void* d_ws, size_t ws_size,
                              hipStream_t stream)
{
    const float* X   = (const float*)d_in[0];
    const float* Y   = (const float*)d_in[1];
    const float* W0s = (const float*)d_in[2];
    const float* bs  = (const float*)d_in[3];
    const float* W0g = (const float*)d_in[4];
    const float* bg  = (const float*)d_in[5];
    const float* W1  = (const float*)d_in[6];
    const float* W2  = (const float*)d_in[7];
    const float* V0  = (const float*)d_in[8];
    const float* bo  = (const float*)d_in[9];
    const float* V1  = (const float*)d_in[10];
    const float* V2  = (const float*)d_in[11];
    short* WP  = (short*)d_ws;           // 331776 B of bf16-packed weights
    float* out = (float*)d_out;

    const int n = in_sizes[0] / 480;     // 200000
    const int tiles = n / 32;            // 6250 32-node tiles (exact)

    prep_weights<<<dim3((WP_TOTAL + 255) / 256), dim3(256), 0, stream>>>(
        W0s, W0g, W1, W2, V0, V1, V2, WP);
    ffn_main<<<dim3(tiles), dim3(512), 0, stream>>>(X, Y, bs, bg, bo, WP, out);
}

// Round 8
// 402.480 us; speedup vs baseline: 1.9108x; 1.9108x over previous
//
#include <hip/hip_runtime.h>

// ---------------------------------------------------------------------------
// Fused equivariant FFN, bf16 MFMA (16x16x32), fp32 accumulate.
// Round 8 = Round 7 structure with __launch_bounds__(512,4).
// R7's (512,6) capped VGPR at 40 -> all prefetched weight fragments spilled
// to scratch (FETCH 198->966MB, WRITE 375->1362MB). This kernel needs ~100+
// live VGPRs for prefetch-and-reuse; (512,4) lets the allocator have them.
// Structure kept from R7: wave-balanced B1/B2 GEMM2s, one prefetched W2
// fragment per wave, x2T staging overlapped with B1-GEMM2(mm=2), ubuf2
// double-buffered so B2-GEMM1(mm+1) overlaps B2-GEMM2(mm).
// ---------------------------------------------------------------------------

typedef __attribute__((ext_vector_type(8))) short short8;   // 8 bf16 = 4 VGPRs
typedef __attribute__((ext_vector_type(4))) float f32x4;

#define INV_M0f 0.08838834764831845f   // 1/sqrt(128)
#define INV_M1f 0.125f                 // 1/sqrt(64)
#define INV_M2f 0.17677669529663687f   // 1/sqrt(32)
#define INV_H0f 0.05103103630798288f   // 1/sqrt(384)
#define INV_H1f 0.07216878364870323f   // 1/sqrt(192)
#define INV_H2f 0.10206207261596577f   // 1/sqrt(96)

// packed bf16 weight offsets inside d_ws (units: shorts), pre-scaled by INV_*
#define OFF_W0T 0         // [672][128]  (W0s|W0g)^T * INV_M0
#define OFF_W1T 86016     // [192][64]   W1^T * INV_M1
#define OFF_W2T 98304     // [96][32]    W2^T * INV_M2
#define OFF_V0T 101376    // [128][384]  V0^T * INV_H0
#define OFF_V1T 150528    // [64][192]   V1^T * INV_H1
#define OFF_V2T 162816    // [32][96]    V2^T * INV_H2
#define WP_TOTAL 165888

__device__ __forceinline__ short f2bf_rne(float f) {        // prep only
    union { float f; unsigned u; } v; v.f = f;
    unsigned r = v.u + 0x7FFFu + ((v.u >> 16) & 1u);
    return (short)(r >> 16);
}
// 1-VALU bf16 convert (RNE) for the hot kernel
__device__ __forceinline__ short f2bf_fast(float f) {
    unsigned r;
    asm("v_cvt_pk_bf16_f32 %0, %1, %1" : "=v"(r) : "v"(f));
    return (short)r;
}
__device__ __forceinline__ float bf2f(short s) {
    union { unsigned u; float f; } v; v.u = ((unsigned)(unsigned short)s) << 16;
    return v.f;
}

__global__ void prep_weights(const float* __restrict__ W0s, const float* __restrict__ W0g,
                             const float* __restrict__ W1,  const float* __restrict__ W2,
                             const float* __restrict__ V0,  const float* __restrict__ V1,
                             const float* __restrict__ V2,  short* __restrict__ ws)
{
    int i = blockIdx.x * 256 + threadIdx.x;
    if (i < 86016) {                    // W0T [672][128]
        int j = i >> 7, k = i & 127;
        float v = (j < 384) ? W0s[k * 384 + j] : W0g[k * 288 + (j - 384)];
        ws[i] = f2bf_rne(v * INV_M0f);
    } else if (i < 98304) {             // W1T [192][64]
        int e = i - 86016; int w = e >> 6, u = e & 63;
        ws[i] = f2bf_rne(W1[u * 192 + w] * INV_M1f);
    } else if (i < 101376) {            // W2T [96][32]
        int e = i - 98304; int w = e >> 5, u = e & 31;
        ws[i] = f2bf_rne(W2[u * 96 + w] * INV_M2f);
    } else if (i < 150528) {            // V0T [128][384]
        int e = i - 101376; int j = e / 384, w = e % 384;
        ws[i] = f2bf_rne(V0[w * 128 + j] * INV_H0f);
    } else if (i < 162816) {            // V1T [64][192]
        int e = i - 150528; int j = e / 192, w = e % 192;
        ws[i] = f2bf_rne(V1[w * 64 + j] * INV_H1f);
    } else if (i < WP_TOTAL) {          // V2T [32][96]
        int e = i - 162816; int j = e / 96, w = e % 96;
        ws[i] = f2bf_rne(V2[w * 32 + j] * INV_H2f);
    }
}

// ---- LDS layout (shorts), 32 nodes, total 26368 shorts = 52736 B ----
// x0s   @     0 : [32][136] = 4352   (start -> end Phase A)
// sbuf  @  4352 : [32][392] = 12544  (Phase A -> Phase D)    [4352,16896)
// gbuf  @ 16896 : [32][296] = 9472   (Phase A -> end)        [16896,26368)
// x1T   @     0 : [3][32][72] = 6912 (after D; overlays dead x0s+sbuf head)
// ubuf1 @  6912 : [32][200] = 6400   (B1; overlays dead sbuf) [6912,13312)
// x2T   @     0 : [5][32][40] = 6400 (staged during B1-G2(2); dead x1T)
// ubuf2A@  6400 : [32][104] = 3328   (B2 double-buffer)       [6400, 9728)
// ubuf2B@  9728 : [32][104] = 3328                            [9728,13056)
#define X0_STRIDE 136
#define SB_OFF 4352
#define SB_STRIDE 392
#define GB_OFF 16896
#define GB_STRIDE 296
#define UB1_OFF 6912
#define UB1_STRIDE 200
#define UB2A_OFF 6400
#define UB2B_OFF 9728
#define UB2_STRIDE 104
#define LDS_SHORTS 26368

#define MFMA(a, b, c) __builtin_amdgcn_mfma_f32_16x16x32_bf16((a), (b), (c), 0, 0, 0)

__global__ __launch_bounds__(512, 4) void ffn_main(
    const float* __restrict__ X, const float* __restrict__ Y,
    const float* __restrict__ bs, const float* __restrict__ bg, const float* __restrict__ bo,
    const short* __restrict__ WP, float* __restrict__ out)
{
    __shared__ short lds[LDS_SHORTS];
    short* x0s   = lds;
    short* sbuf  = lds + SB_OFF;
    short* gbuf  = lds + GB_OFF;
    short* x1T   = lds;
    short* x2T   = lds;
    short* ubuf1 = lds + UB1_OFF;
    short* ubuf2A = lds + UB2A_OFF;
    short* ubuf2B = lds + UB2B_OFF;

    const int tid  = threadIdx.x;
    const int wid  = tid >> 6;     // wave 0..7
    const int lane = tid & 63;
    const int m    = lane & 15;    // A-row / B-col / D-col index
    const int bq   = lane >> 4;    // k-block; D row-group
    const int n0   = blockIdx.x * 32;

    // ---- prefetch first Phase-A weight tile (overlaps x0 staging) ----
    short8 w0c[4];
    float bias_c;
    {
        const short* w = WP + OFF_W0T + (wid * 16 + m) * 128 + bq * 8;
        #pragma unroll
        for (int k = 0; k < 4; ++k) w0c[k] = *(const short8*)(w + k * 32);
        bias_c = bs[wid * 16 + m];          // first jt = wid < 24 -> always bs
    }

    // ---- stage x0 (32 nodes x 128 cols) -> LDS bf16, coalesced ----
    {
        const int node = tid >> 4, c16 = tid & 15;
        const float* xp = X + (size_t)(n0 + node) * 480 + c16 * 8;
        float4 f0 = *(const float4*)xp;
        float4 f1 = *(const float4*)(xp + 4);
        short8 a;
        a[0]=f2bf_fast(f0.x); a[1]=f2bf_fast(f0.y); a[2]=f2bf_fast(f0.z); a[3]=f2bf_fast(f0.w);
        a[4]=f2bf_fast(f1.x); a[5]=f2bf_fast(f1.y); a[6]=f2bf_fast(f1.z); a[7]=f2bf_fast(f1.w);
        *(short8*)(x0s + node * X0_STRIDE + c16 * 8) = a;
    }

    // y for the 8 rows this lane touches: rows t*16 + bq*4 + r
    float yv[2][4];
    #pragma unroll
    for (int t = 0; t < 2; ++t)
        #pragma unroll
        for (int r = 0; r < 4; ++r)
            yv[t][r] = Y[n0 + t * 16 + bq * 4 + r];

    __syncthreads();                                        // [b1]

    // x0 A-fragments, both row-tiles
    short8 a0[2][4];
    #pragma unroll
    for (int t = 0; t < 2; ++t)
        #pragma unroll
        for (int k = 0; k < 4; ++k)
            a0[t][k] = *(const short8*)(x0s + (t * 16 + m) * X0_STRIDE + k * 32 + bq * 8);

    // ---- Phase A: pre(32x672) = x0 @ W0T^T ; s -> sbuf, g -> gbuf ----
    #pragma unroll 1
    for (int i = 0; i < 6; ++i) {
        const int jt = wid + i * 8;
        if (jt >= 42) break;
        const int jn = jt + 8;
        short8 w0n[4];
        float bias_n = 0.f;
        if (jn < 42) {
            const short* w = WP + OFF_W0T + (jn * 16 + m) * 128 + bq * 8;
            #pragma unroll
            for (int k = 0; k < 4; ++k) w0n[k] = *(const short8*)(w + k * 32);
            bias_n = (jn < 24) ? bs[jn * 16 + m] : bg[(jn - 24) * 16 + m];
        }
        f32x4 acc0 = {0.f,0.f,0.f,0.f}, acc1 = {0.f,0.f,0.f,0.f};
        #pragma unroll
        for (int k = 0; k < 4; ++k) {
            acc0 = MFMA(a0[0][k], w0c[k], acc0);
            acc1 = MFMA(a0[1][k], w0c[k], acc1);
        }
        if (jt < 24) {          // silu -> sbuf
            #pragma unroll
            for (int t = 0; t < 2; ++t) {
                f32x4 acc = t ? acc1 : acc0;
                #pragma unroll
                for (int r = 0; r < 4; ++r) {
                    float val = fmaf(acc[r], yv[t][r], bias_c);
                    float e   = __expf(-val);
                    float sv  = val * __builtin_amdgcn_rcpf(1.f + e);
                    sbuf[(t * 16 + bq * 4 + r) * SB_STRIDE + jt * 16 + m] = f2bf_fast(sv);
                }
            }
        } else {                // sigmoid -> gbuf
            #pragma unroll
            for (int t = 0; t < 2; ++t) {
                f32x4 acc = t ? acc1 : acc0;
                #pragma unroll
                for (int r = 0; r < 4; ++r) {
                    float val = fmaf(acc[r], yv[t][r], bias_c);
                    float e   = __expf(-val);
                    float sg  = __builtin_amdgcn_rcpf(1.f + e);
                    gbuf[(t * 16 + bq * 4 + r) * GB_STRIDE + (jt - 24) * 16 + m] = f2bf_fast(sg);
                }
            }
        }
        #pragma unroll
        for (int k = 0; k < 4; ++k) w0c[k] = w0n[k];
        bias_c = bias_n;
    }

    // ---- prefetch Phase-D weights (V0T) + bias before the barrier ----
    short8 v0f[12];
    {
        const short* v = WP + OFF_V0T + (wid * 16 + m) * 384 + bq * 8;
        #pragma unroll
        for (int k = 0; k < 12; ++k) v0f[k] = *(const short8*)(v + k * 32);
    }
    const float bo_r = bo[wid * 16 + m];
    __syncthreads();                                        // [b2]

    // ---- Phase D: o0(32x128) = s @ V0 ; 1 j-tile per wave, dense stores ----
    {
        f32x4 accD0 = {0.f,0.f,0.f,0.f}, accD1 = {0.f,0.f,0.f,0.f};
        #pragma unroll
        for (int k = 0; k < 12; ++k) {
            short8 sa0 = *(const short8*)(sbuf + m * SB_STRIDE + k * 32 + bq * 8);
            short8 sa1 = *(const short8*)(sbuf + (16 + m) * SB_STRIDE + k * 32 + bq * 8);
            accD0 = MFMA(sa0, v0f[k], accD0);
            accD1 = MFMA(sa1, v0f[k], accD1);
        }
        #pragma unroll
        for (int t = 0; t < 2; ++t) {
            f32x4 acc = t ? accD1 : accD0;
            #pragma unroll
            for (int r = 0; r < 4; ++r)
                out[(size_t)(n0 + t * 16 + bq * 4 + r) * 480 + wid * 16 + m] =
                    fmaf(acc[r], yv[t][r], bo_r);
        }
    }

    // ---- prefetch B1/B2 weights while D's sbuf reads drain ----
    // B1-GEMM1: waves get j-pairs jt = wid (+8)
    short8 w1f[2][2];
    #pragma unroll
    for (int jj = 0; jj < 2; ++jj) {
        const int jt = wid + jj * 8;
        if (jt < 12) {
            const short* w = WP + OFF_W1T + (jt * 16 + m) * 64 + bq * 8;
            w1f[jj][0] = *(const short8*)(w);
            w1f[jj][1] = *(const short8*)(w + 32);
        }
    }
    // B1-GEMM2: all 8 waves, unit (ct1 = wid&3, t1 = wid>>2)
    const int ct1 = wid & 3, t1 = wid >> 2;
    short8 v1f[6];
    {
        const short* v = WP + OFF_V1T + (ct1 * 16 + m) * 192 + bq * 8;
        #pragma unroll
        for (int k = 0; k < 6; ++k) v1f[k] = *(const short8*)(v + k * 32);
    }
    // B2-GEMM1: each wave exactly one W2 j-tile:
    //   wid>=4: jt2 = wid-4, row-tiles {0,1}; wid<4: jt2 = 4+(wid>>1), rt = wid&1
    const int jt2 = (wid >= 4) ? (wid - 4) : (4 + (wid >> 1));
    const short8 w2f = *(const short8*)(WP + OFF_W2T + (jt2 * 16 + m) * 32 + bq * 8);
    // B2-GEMM2: waves 0..3, unit (ct2 = wid&1, t2 = wid>>1)
    const int ct2 = wid & 1, t2 = wid >> 1;
    short8 v2f[3];
    if (wid < 4) {
        const short* v = WP + OFF_V2T + (ct2 * 16 + m) * 96 + bq * 8;
        #pragma unroll
        for (int k = 0; k < 3; ++k) v2f[k] = *(const short8*)(v + k * 32);
    }
    // per-lane y rows with wave-static selects (no dynamic reg indexing)
    float y_t1[4], y_t2[4];
    #pragma unroll
    for (int r = 0; r < 4; ++r) {
        y_t1[r] = t1 ? yv[1][r] : yv[0][r];
        y_t2[r] = t2 ? yv[1][r] : yv[0][r];
    }
    __syncthreads();   // [b3] sbuf reads done; x1T region may be written

    // ---- stage x1 as [3][32][72]: plane mm, row node ----
    {
        const int node = tid >> 4, c16 = tid & 15;
        const float* xp = X + (size_t)(n0 + node) * 480 + 128 + c16 * 12;
        float4 fa = *(const float4*)xp;
        float4 fb = *(const float4*)(xp + 4);
        float4 fc = *(const float4*)(xp + 8);
        float vals[12] = {fa.x,fa.y,fa.z,fa.w, fb.x,fb.y,fb.z,fb.w, fc.x,fc.y,fc.z,fc.w};
        #pragma unroll
        for (int c = 0; c < 12; ++c) {
            const int u   = c16 * 4 + c / 3;    // static per c
            const int mmv = c % 3;
            x1T[mmv * 2304 + node * 72 + u] = f2bf_fast(vals[c]);
        }
    }
    __syncthreads();                                        // [b4]

    // ---- Phase B1: per mm: GEMM1 (gate) -> ubuf1 ; GEMM2 -> registers ----
    f32x4 o1f[3];
    #pragma unroll
    for (int mm = 0; mm < 3; ++mm) {
        // GEMM1: v1_mm(32x192) = x1_mm @ W1 ; j-pairs over waves (prefetched w1f)
        #pragma unroll
        for (int jj = 0; jj < 2; ++jj) {
            const int jt = wid + jj * 8;
            if (jt < 12) {
                f32x4 accA = {0.f,0.f,0.f,0.f}, accB = {0.f,0.f,0.f,0.f};
                short8 a00 = *(const short8*)(x1T + mm * 2304 + m * 72 + bq * 8);
                short8 a01 = *(const short8*)(x1T + mm * 2304 + m * 72 + 32 + bq * 8);
                short8 a10 = *(const short8*)(x1T + mm * 2304 + (16 + m) * 72 + bq * 8);
                short8 a11 = *(const short8*)(x1T + mm * 2304 + (16 + m) * 72 + 32 + bq * 8);
                accA = MFMA(a00, w1f[jj][0], accA);
                accA = MFMA(a01, w1f[jj][1], accA);
                accB = MFMA(a10, w1f[jj][0], accB);
                accB = MFMA(a11, w1f[jj][1], accB);
                #pragma unroll
                for (int t = 0; t < 2; ++t) {
                    f32x4 acc = t ? accB : accA;
                    #pragma unroll
                    for (int r = 0; r < 4; ++r) {
                        const int node = t * 16 + bq * 4 + r;
                        float gv = bf2f(gbuf[node * GB_STRIDE + jt * 16 + m]);
                        ubuf1[node * UB1_STRIDE + jt * 16 + m] =
                            f2bf_fast(acc[r] * yv[t][r] * gv);
                    }
                }
            }
        }
        __syncthreads();                                    // ubuf1 ready
        // x2 global loads issued early (mm==2 only), hidden under GEMM2 MFMAs
        float xv2[10];
        if (mm == 2) {
            const int node2 = tid >> 4, c16 = tid & 15;
            const float* xp2 = X + (size_t)(n0 + node2) * 480 + 320 + c16 * 10;
            #pragma unroll
            for (int p = 0; p < 5; ++p) {
                float2 f = *(const float2*)(xp2 + p * 2);
                xv2[p * 2] = f.x; xv2[p * 2 + 1] = f.y;
            }
        }
        // GEMM2: o1_mm(32x64) = u @ V1 ; all 8 waves, unit (ct1,t1)
        {
            f32x4 acc = {0.f,0.f,0.f,0.f};
            #pragma unroll
            for (int k = 0; k < 6; ++k) {
                short8 a = *(const short8*)(ubuf1 + (t1 * 16 + m) * UB1_STRIDE + k * 32 + bq * 8);
                acc = MFMA(a, v1f[k], acc);
            }
            o1f[mm] = acc;
        }
        // x2T staging writes (mm==2): x1T fully dead after this mm's GEMM1
        if (mm == 2) {
            const int node2 = tid >> 4, c16 = tid & 15;
            #pragma unroll
            for (int c = 0; c < 10; ++c) {
                const int u   = c16 * 2 + c / 5;    // static per c
                const int mmv = c % 5;
                x2T[(mmv * 1280) + node2 * 40 + u] = f2bf_fast(xv2[c]);
            }
        }
        __syncthreads();   // protects ubuf1 rewrite (mm<2) / x2T+ubuf2A (mm==2)
    }
    // dense o1 stores: 12 B contiguous per (node, j)
    #pragma unroll
    for (int r = 0; r < 4; ++r) {
        const float yy = y_t1[r];
        float* pp = out + (size_t)(n0 + t1 * 16 + bq * 4 + r) * 480 + 128 + (ct1 * 16 + m) * 3;
        pp[0] = o1f[0][r] * yy; pp[1] = o1f[1][r] * yy; pp[2] = o1f[2][r] * yy;
    }

    // ---- Phase B2: double-buffered ubuf2; G1(mm+1) overlaps G2(mm) ----
    // B2-GEMM1 for plane mmv into dst
    auto b2_g1 = [&](int mmv, short* dst) {
        #pragma unroll
        for (int q = 0; q < 2; ++q) {
            if (q == 0 || wid >= 4) {
                const int rt = (wid >= 4) ? q : (wid & 1);
                short8 a = *(const short8*)(x2T + mmv * 1280 + (rt * 16 + m) * 40 + bq * 8);
                f32x4 z = {0.f,0.f,0.f,0.f};
                f32x4 acc = MFMA(a, w2f, z);
                #pragma unroll
                for (int r = 0; r < 4; ++r) {
                    const int node = rt * 16 + bq * 4 + r;
                    const float yy = rt ? yv[1][r] : yv[0][r];
                    float gv = bf2f(gbuf[node * GB_STRIDE + 192 + jt2 * 16 + m]);
                    dst[node * UB2_STRIDE + jt2 * 16 + m] = f2bf_fast(acc[r] * yy * gv);
                }
            }
        }
    };

    b2_g1(0, ubuf2A);
    __syncthreads();                                        // bufA ready

    f32x4 o2f[5];
    #pragma unroll
    for (int mm = 0; mm < 5; ++mm) {
        if (mm < 4) b2_g1(mm + 1, (mm & 1) ? ubuf2A : ubuf2B);  // buf[(mm+1)&1]
        if (wid < 4) {                  // GEMM2 from buf[mm&1]
            const short* src = (mm & 1) ? ubuf2B : ubuf2A;
            f32x4 acc = {0.f,0.f,0.f,0.f};
            #pragma unroll
            for (int k = 0; k < 3; ++k) {
                short8 a = *(const short8*)(src + (t2 * 16 + m) * UB2_STRIDE + k * 32 + bq * 8);
                acc = MFMA(a, v2f[k], acc);
            }
            o2f[mm] = acc;
        }
        if (mm < 4) __syncthreads();
    }
    // dense o2 stores: 20 B contiguous per (node, j)
    if (wid < 4) {
        #pragma unroll
        for (int r = 0; r < 4; ++r) {
            const float yy = y_t2[r];
            float* pp = out + (size_t)(n0 + t2 * 16 + bq * 4 + r) * 480 + 320 + (ct2 * 16 + m) * 5;
            pp[0] = o2f[0][r] * yy; pp[1] = o2f[1][r] * yy; pp[2] = o2f[2][r] * yy;
            pp[3] = o2f[3][r] * yy; pp[4] = o2f[4][r] * yy;
        }
    }
}

extern "C" void kernel_launch(void* const* d_in, const int* in_sizes, int n_in,
                              void* d_out, int out_size, void* d_ws, size_t ws_size,
                              hipStream_t stream)
{
    const float* X   = (const float*)d_in[0];
    const float* Y   = (const float*)d_in[1];
    const float* W0s = (const float*)d_in[2];
    const float* bs  = (const float*)d_in[3];
    const float* W0g = (const float*)d_in[4];
    const float* bg  = (const float*)d_in[5];
    const float* W1  = (const float*)d_in[6];
    const float* W2  = (const float*)d_in[7];
    const float* V0  = (const float*)d_in[8];
    const float* bo  = (const float*)d_in[9];
    const float* V1  = (const float*)d_in[10];
    const float* V2  = (const float*)d_in[11];
    short* WP  = (short*)d_ws;           // 331776 B of bf16-packed weights
    float* out = (float*)d_out;

    const int n = in_sizes[0] / 480;     // 200000
    const int tiles = n / 32;            // 6250 32-node tiles (exact)

    prep_weights<<<dim3((WP_TOTAL + 255) / 256), dim3(256), 0, stream>>>(
        W0s, W0g, W1, W2, V0, V1, V2, WP);
    ffn_main<<<dim3(tiles), dim3(512), 0, stream>>>(X, Y, bs, bg, bo, WP, out);
}

// Round 11
// 334.351 us; speedup vs baseline: 2.3002x; 1.2038x over previous
//
#include <hip/hip_runtime.h>

// ---------------------------------------------------------------------------
// Fused equivariant FFN, bf16 MFMA (16x16x32), fp32 accumulate.
// Round 11 = EXACT Round-5 source (best known good: 334us, absmax 0.0156).
// Re-anchor after R9/R10's x1-hoist miscompile-class failures (hoisted loads
// are semantically identical but fail with absmax ~69 -> do NOT hoist X-data
// registers across Phase A in this kernel).
// 32 nodes/block, 8 waves, 2 row-tiles/wave (MFMA:B-load = 2:1),
// software-pipelined weight loads, INV_* folded into prepacked weights,
// 1-op bf16 cvt via v_cvt_pk_bf16_f32, o1/o2 register-accumulated across mm
// for dense stores.
// ---------------------------------------------------------------------------

typedef __attribute__((ext_vector_type(8))) short short8;   // 8 bf16 = 4 VGPRs
typedef __attribute__((ext_vector_type(4))) float f32x4;

#define INV_M0f 0.08838834764831845f   // 1/sqrt(128)
#define INV_M1f 0.125f                 // 1/sqrt(64)
#define INV_M2f 0.17677669529663687f   // 1/sqrt(32)
#define INV_H0f 0.05103103630798288f   // 1/sqrt(384)
#define INV_H1f 0.07216878364870323f   // 1/sqrt(192)
#define INV_H2f 0.10206207261596577f   // 1/sqrt(96)

// packed bf16 weight offsets inside d_ws (units: shorts). All prescaled by
// their INV_* constant so epilogues do val = fma(acc, y, bias) / acc*y.
#define OFF_W0T 0         // [672][128]  (W0s|W0g)^T * INV_M0
#define OFF_W1T 86016     // [192][64]   W1^T * INV_M1
#define OFF_W2T 98304     // [96][32]    W2^T * INV_M2
#define OFF_V0T 101376    // [128][384]  V0^T * INV_H0
#define OFF_V1T 150528    // [64][192]   V1^T * INV_H1
#define OFF_V2T 162816    // [32][96]    V2^T * INV_H2
#define WP_TOTAL 165888

__device__ __forceinline__ short f2bf_rne(float f) {        // prep only
    union { float f; unsigned u; } v; v.f = f;
    unsigned r = v.u + 0x7FFFu + ((v.u >> 16) & 1u);
    return (short)(r >> 16);
}
// 1-VALU bf16 convert (RNE) for the hot kernel
__device__ __forceinline__ short f2bf_fast(float f) {
    unsigned r;
    asm("v_cvt_pk_bf16_f32 %0, %1, %1" : "=v"(r) : "v"(f));
    return (short)r;
}
__device__ __forceinline__ float bf2f(short s) {
    union { unsigned u; float f; } v; v.u = ((unsigned)(unsigned short)s) << 16;
    return v.f;
}

__global__ void prep_weights(const float* __restrict__ W0s, const float* __restrict__ W0g,
                             const float* __restrict__ W1,  const float* __restrict__ W2,
                             const float* __restrict__ V0,  const float* __restrict__ V1,
                             const float* __restrict__ V2,  short* __restrict__ ws)
{
    int i = blockIdx.x * 256 + threadIdx.x;
    if (i < 86016) {                    // W0T [672][128]
        int j = i >> 7, k = i & 127;
        float v = (j < 384) ? W0s[k * 384 + j] : W0g[k * 288 + (j - 384)];
        ws[i] = f2bf_rne(v * INV_M0f);
    } else if (i < 98304) {             // W1T [192][64]
        int e = i - 86016; int w = e >> 6, u = e & 63;
        ws[i] = f2bf_rne(W1[u * 192 + w] * INV_M1f);
    } else if (i < 101376) {            // W2T [96][32]
        int e = i - 98304; int w = e >> 5, u = e & 31;
        ws[i] = f2bf_rne(W2[u * 96 + w] * INV_M2f);
    } else if (i < 150528) {            // V0T [128][384]
        int e = i - 101376; int j = e / 384, w = e % 384;
        ws[i] = f2bf_rne(V0[w * 128 + j] * INV_H0f);
    } else if (i < 162816) {            // V1T [64][192]
        int e = i - 150528; int j = e / 192, w = e % 192;
        ws[i] = f2bf_rne(V1[w * 64 + j] * INV_H1f);
    } else if (i < WP_TOTAL) {          // V2T [32][96]
        int e = i - 162816; int j = e / 96, w = e % 96;
        ws[i] = f2bf_rne(V2[w * 32 + j] * INV_H2f);
    }
}

// ---- LDS layout (shorts), 32 nodes, total 26368 shorts = 52736 B ----
// x0s  @     0 : [32][136] = 4352   (start -> end Phase A)
// sbuf @  4352 : [32][392] = 12544  (Phase A -> Phase D)    [4352,16896)
// gbuf @ 16896 : [32][296] = 9472   (Phase A -> end)        [16896,26368)
// x1T  @     0 : [3][32][72] = 6912 (after D; overlays dead x0s+sbuf head)
// x2T  @     0 : [5][32][40] = 6400 (after B1; overlays dead x1T)
// ubuf @  6912 : [32][200] = 6400   (B phases; overlays dead sbuf) [6912,13312)
#define X0_STRIDE 136
#define SB_OFF 4352
#define SB_STRIDE 392
#define GB_OFF 16896
#define GB_STRIDE 296
#define UB_OFF 6912
#define UB_STRIDE 200
#define LDS_SHORTS 26368

#define MFMA(a, b, c) __builtin_amdgcn_mfma_f32_16x16x32_bf16((a), (b), (c), 0, 0, 0)

__global__ __launch_bounds__(512, 4) void ffn_main(
    const float* __restrict__ X, const float* __restrict__ Y,
    const float* __restrict__ bs, const float* __restrict__ bg, const float* __restrict__ bo,
    const short* __restrict__ WP, float* __restrict__ out)
{
    __shared__ short lds[LDS_SHORTS];
    short* x0s  = lds;
    short* sbuf = lds + SB_OFF;
    short* gbuf = lds + GB_OFF;
    short* x1T  = lds;
    short* x2T  = lds;
    short* ubuf = lds + UB_OFF;

    const int tid  = threadIdx.x;
    const int wid  = tid >> 6;     // wave 0..7
    const int lane = tid & 63;
    const int m    = lane & 15;    // A-row(node) / B-row(out-col) index
    const int bq   = lane >> 4;    // k-block; D row-group
    const int n0   = blockIdx.x * 32;

    // ---- prefetch first Phase-A weight tile (overlaps x0 staging) ----
    short8 w0c[4];
    float bias_c;
    {
        const short* w = WP + OFF_W0T + (wid * 16 + m) * 128 + bq * 8;
        #pragma unroll
        for (int k = 0; k < 4; ++k) w0c[k] = *(const short8*)(w + k * 32);
        bias_c = bs[wid * 16 + m];          // first jt = wid < 24 -> always bs
    }

    // ---- stage x0 (32 nodes x 128 cols) -> LDS bf16, coalesced ----
    {
        const int node = tid >> 4, c16 = tid & 15;
        const float* xp = X + (size_t)(n0 + node) * 480 + c16 * 8;
        float4 f0 = *(const float4*)xp;
        float4 f1 = *(const float4*)(xp + 4);
        short8 a;
        a[0]=f2bf_fast(f0.x); a[1]=f2bf_fast(f0.y); a[2]=f2bf_fast(f0.z); a[3]=f2bf_fast(f0.w);
        a[4]=f2bf_fast(f1.x); a[5]=f2bf_fast(f1.y); a[6]=f2bf_fast(f1.z); a[7]=f2bf_fast(f1.w);
        *(short8*)(x0s + node * X0_STRIDE + c16 * 8) = a;
    }

    // y for the 8 output rows this lane touches: rows t*16 + bq*4 + r
    float yv[2][4];
    #pragma unroll
    for (int t = 0; t < 2; ++t)
        #pragma unroll
        for (int r = 0; r < 4; ++r)
            yv[t][r] = Y[n0 + t * 16 + bq * 4 + r];

    __syncthreads();

    // x0 A-fragments, both row-tiles
    short8 a0[2][4];
    #pragma unroll
    for (int t = 0; t < 2; ++t)
        #pragma unroll
        for (int k = 0; k < 4; ++k)
            a0[t][k] = *(const short8*)(x0s + (t * 16 + m) * X0_STRIDE + k * 32 + bq * 8);

    // ---- Phase A: pre(32x672) = x0 @ W0T^T ; s -> sbuf, g -> gbuf ----
    // jt = wid + 8i, software-pipelined B-fragments (1 tile ahead)
    #pragma unroll 1
    for (int i = 0; i < 6; ++i) {
        const int jt = wid + i * 8;
        if (jt >= 42) break;
        const int jn = jt + 8;
        short8 w0n[4];
        float bias_n = 0.f;
        if (jn < 42) {
            const short* w = WP + OFF_W0T + (jn * 16 + m) * 128 + bq * 8;
            #pragma unroll
            for (int k = 0; k < 4; ++k) w0n[k] = *(const short8*)(w + k * 32);
            bias_n = (jn < 24) ? bs[jn * 16 + m] : bg[(jn - 24) * 16 + m];
        }
        f32x4 acc0 = {0.f,0.f,0.f,0.f}, acc1 = {0.f,0.f,0.f,0.f};
        #pragma unroll
        for (int k = 0; k < 4; ++k) {
            acc0 = MFMA(a0[0][k], w0c[k], acc0);
            acc1 = MFMA(a0[1][k], w0c[k], acc1);
        }
        if (jt < 24) {          // silu -> sbuf, col j = jt*16+m
            #pragma unroll
            for (int t = 0; t < 2; ++t) {
                f32x4 acc = t ? acc1 : acc0;
                #pragma unroll
                for (int r = 0; r < 4; ++r) {
                    float val = fmaf(acc[r], yv[t][r], bias_c);
                    float e   = __expf(-val);
                    float sv  = val * __builtin_amdgcn_rcpf(1.f + e);
                    sbuf[(t * 16 + bq * 4 + r) * SB_STRIDE + jt * 16 + m] = f2bf_fast(sv);
                }
            }
        } else {                // sigmoid -> gbuf, col (jt-24)*16+m
            #pragma unroll
            for (int t = 0; t < 2; ++t) {
                f32x4 acc = t ? acc1 : acc0;
                #pragma unroll
                for (int r = 0; r < 4; ++r) {
                    float val = fmaf(acc[r], yv[t][r], bias_c);
                    float e   = __expf(-val);
                    float sg  = __builtin_amdgcn_rcpf(1.f + e);
                    gbuf[(t * 16 + bq * 4 + r) * GB_STRIDE + (jt - 24) * 16 + m] = f2bf_fast(sg);
                }
            }
        }
        #pragma unroll
        for (int k = 0; k < 4; ++k) w0c[k] = w0n[k];
        bias_c = bias_n;
    }

    // ---- prefetch Phase-D weights (V0T) + bias before the barrier ----
    short8 v0f[12];
    {
        const short* v = WP + OFF_V0T + (wid * 16 + m) * 384 + bq * 8;
        #pragma unroll
        for (int k = 0; k < 12; ++k) v0f[k] = *(const short8*)(v + k * 32);
    }
    const float bo_r = bo[wid * 16 + m];
    __syncthreads();

    // ---- Phase D: o0(32x128) = s @ V0 ; 1 j-tile per wave ----
    {
        f32x4 accD0 = {0.f,0.f,0.f,0.f}, accD1 = {0.f,0.f,0.f,0.f};
        #pragma unroll
        for (int k = 0; k < 12; ++k) {
            short8 sa0 = *(const short8*)(sbuf + m * SB_STRIDE + k * 32 + bq * 8);
            short8 sa1 = *(const short8*)(sbuf + (16 + m) * SB_STRIDE + k * 32 + bq * 8);
            accD0 = MFMA(sa0, v0f[k], accD0);
            accD1 = MFMA(sa1, v0f[k], accD1);
        }
        #pragma unroll
        for (int t = 0; t < 2; ++t) {
            f32x4 acc = t ? accD1 : accD0;
            #pragma unroll
            for (int r = 0; r < 4; ++r)
                out[(size_t)(n0 + t * 16 + bq * 4 + r) * 480 + wid * 16 + m] =
                    fmaf(acc[r], yv[t][r], bo_r);
        }
    }

    // ---- prefetch B1 weights (hoisted across all 3 mm) ----
    short8 w1f[2][2];                   // [jj][k4], jt = wid + jj*8 (<12)
    #pragma unroll
    for (int jj = 0; jj < 2; ++jj) {
        const int jt = wid + jj * 8;
        if (jt < 12) {
            const short* w = WP + OFF_W1T + (jt * 16 + m) * 64 + bq * 8;
            w1f[jj][0] = *(const short8*)(w);
            w1f[jj][1] = *(const short8*)(w + 32);
        }
    }
    short8 v1f[6];                      // waves 4..7: V1T j-tile (wid-4)
    if (wid >= 4) {
        const short* v = WP + OFF_V1T + ((wid - 4) * 16 + m) * 192 + bq * 8;
        #pragma unroll
        for (int k = 0; k < 6; ++k) v1f[k] = *(const short8*)(v + k * 32);
    }
    __syncthreads();   // sbuf now dead; x1T region may be written

    // ---- stage x1 transposed: x1T[mm][node][u], u<64 pad 72 ----
    {
        const int node = tid >> 4, c16 = tid & 15;
        const float* xp = X + (size_t)(n0 + node) * 480 + 128 + c16 * 12;
        float4 fa = *(const float4*)xp;
        float4 fb = *(const float4*)(xp + 4);
        float4 fc = *(const float4*)(xp + 8);
        float vals[12] = {fa.x,fa.y,fa.z,fa.w, fb.x,fb.y,fb.z,fb.w, fc.x,fc.y,fc.z,fc.w};
        #pragma unroll
        for (int c = 0; c < 12; ++c) {
            const int u   = c16 * 4 + c / 3;    // static per c (c16*12 % 3 == 0)
            const int mmv = c % 3;
            x1T[mmv * 2304 + node * 72 + u] = f2bf_fast(vals[c]);
        }
    }
    __syncthreads();

    // ---- Phase B1: 3 components; GEMM1 (gate) -> ubuf; GEMM2 -> regs ----
    float o1a[3][2][4];                 // waves 4..7 accumulate all mm
    #pragma unroll
    for (int mm = 0; mm < 3; ++mm) {
        // GEMM1: v1_mm(32x192), j-tiles 0..11 (waves 0-3 take 2, 4-7 take 1)
        #pragma unroll
        for (int jj = 0; jj < 2; ++jj) {
            const int jt = wid + jj * 8;
            if (jt < 12) {
                f32x4 accA = {0.f,0.f,0.f,0.f}, accB = {0.f,0.f,0.f,0.f};
                short8 a00 = *(const short8*)(x1T + mm * 2304 + m * 72 + bq * 8);
                short8 a01 = *(const short8*)(x1T + mm * 2304 + m * 72 + 32 + bq * 8);
                short8 a10 = *(const short8*)(x1T + mm * 2304 + (16 + m) * 72 + bq * 8);
                short8 a11 = *(const short8*)(x1T + mm * 2304 + (16 + m) * 72 + 32 + bq * 8);
                accA = MFMA(a00, w1f[jj][0], accA);
                accA = MFMA(a01, w1f[jj][1], accA);
                accB = MFMA(a10, w1f[jj][0], accB);
                accB = MFMA(a11, w1f[jj][1], accB);
                #pragma unroll
                for (int t = 0; t < 2; ++t) {
                    f32x4 acc = t ? accB : accA;
                    #pragma unroll
                    for (int r = 0; r < 4; ++r) {
                        const int node = t * 16 + bq * 4 + r;
                        float gv = bf2f(gbuf[node * GB_STRIDE + jt * 16 + m]);
                        ubuf[node * UB_STRIDE + jt * 16 + m] =
                            f2bf_fast(acc[r] * yv[t][r] * gv);
                    }
                }
            }
        }
        __syncthreads();
        // GEMM2: o1_mm(32x64) = u @ V1 ; waves 4..7, j-tile (wid-4)
        if (wid >= 4) {
            f32x4 accA = {0.f,0.f,0.f,0.f}, accB = {0.f,0.f,0.f,0.f};
            #pragma unroll
            for (int k = 0; k < 6; ++k) {
                short8 au0 = *(const short8*)(ubuf + m * UB_STRIDE + k * 32 + bq * 8);
                short8 au1 = *(const short8*)(ubuf + (16 + m) * UB_STRIDE + k * 32 + bq * 8);
                accA = MFMA(au0, v1f[k], accA);
                accB = MFMA(au1, v1f[k], accB);
            }
            #pragma unroll
            for (int t = 0; t < 2; ++t) {
                f32x4 acc = t ? accB : accA;
                #pragma unroll
                for (int r = 0; r < 4; ++r)
                    o1a[mm][t][r] = acc[r] * yv[t][r];
            }
        }
        __syncthreads();
    }
    // dense o1 stores: 12B contiguous per lane per row
    if (wid >= 4) {
        const int jc = (wid - 4) * 16 + m;
        #pragma unroll
        for (int t = 0; t < 2; ++t)
            #pragma unroll
            for (int r = 0; r < 4; ++r) {
                float* p = out + (size_t)(n0 + t * 16 + bq * 4 + r) * 480 + 128 + jc * 3;
                p[0] = o1a[0][t][r]; p[1] = o1a[1][t][r]; p[2] = o1a[2][t][r];
            }
    }

    // ---- prefetch B2 weights ----
    short8 w2f;                          // waves 0..5: W2T j-tile wid
    if (wid < 6)
        w2f = *(const short8*)(WP + OFF_W2T + (wid * 16 + m) * 32 + bq * 8);
    short8 v2f[3];                       // waves 6..7: V2T j-tile (wid-6)
    if (wid >= 6) {
        const short* v = WP + OFF_V2T + ((wid - 6) * 16 + m) * 96 + bq * 8;
        #pragma unroll
        for (int k = 0; k < 3; ++k) v2f[k] = *(const short8*)(v + k * 32);
    }

    // ---- stage x2 transposed: x2T[mm][node][u], u<32 pad 40 ----
    {
        const int node = tid >> 4, c16 = tid & 15;
        const float* xp = X + (size_t)(n0 + node) * 480 + 320 + c16 * 10;
        float vals[10];
        #pragma unroll
        for (int p = 0; p < 5; ++p) {
            float2 f = *(const float2*)(xp + p * 2);
            vals[p * 2] = f.x; vals[p * 2 + 1] = f.y;
        }
        #pragma unroll
        for (int c = 0; c < 10; ++c) {
            const int u   = c16 * 2 + c / 5;    // static per c (c16*10 % 5 == 0)
            const int mmv = c % 5;
            x2T[mmv * 1280 + node * 40 + u] = f2bf_fast(vals[c]);
        }
    }
    __syncthreads();

    // ---- Phase B2: 5 components; GEMM1 (gate) -> ubuf; GEMM2 -> regs ----
    float o2a[5][2][4];                 // waves 6..7
    #pragma unroll
    for (int mm = 0; mm < 5; ++mm) {
        if (wid < 6) {                  // GEMM1: v2_mm(32x96), j-tile wid
            f32x4 accA = {0.f,0.f,0.f,0.f}, accB = {0.f,0.f,0.f,0.f};
            short8 a20 = *(const short8*)(x2T + mm * 1280 + m * 40 + bq * 8);
            short8 a21 = *(const short8*)(x2T + mm * 1280 + (16 + m) * 40 + bq * 8);
            accA = MFMA(a20, w2f, accA);
            accB = MFMA(a21, w2f, accB);
            #pragma unroll
            for (int t = 0; t < 2; ++t) {
                f32x4 acc = t ? accB : accA;
                #pragma unroll
                for (int r = 0; r < 4; ++r) {
                    const int node = t * 16 + bq * 4 + r;
                    float gv = bf2f(gbuf[node * GB_STRIDE + 192 + wid * 16 + m]);
                    ubuf[node * UB_STRIDE + wid * 16 + m] =
                        f2bf_fast(acc[r] * yv[t][r] * gv);
                }
            }
        }
        __syncthreads();
        if (wid >= 6) {                 // GEMM2: o2_mm(32x32) = u2 @ V2, K=96
            f32x4 accA = {0.f,0.f,0.f,0.f}, accB = {0.f,0.f,0.f,0.f};
            #pragma unroll
            for (int k = 0; k < 3; ++k) {
                short8 au0 = *(const short8*)(ubuf + m * UB_STRIDE + k * 32 + bq * 8);
                short8 au1 = *(const short8*)(ubuf + (16 + m) * UB_STRIDE + k * 32 + bq * 8);
                accA = MFMA(au0, v2f[k], accA);
                accB = MFMA(au1, v2f[k], accB);
            }
            #pragma unroll
            for (int t = 0; t < 2; ++t) {
                f32x4 acc = t ? accB : accA;
                #pragma unroll
                for (int r = 0; r < 4; ++r)
                    o2a[mm][t][r] = acc[r] * yv[t][r];
            }
        }
        if (mm < 4) __syncthreads();
    }
    // dense o2 stores: 20B contiguous per lane per row
    if (wid >= 6) {
        const int jc = (wid - 6) * 16 + m;
        #pragma unroll
        for (int t = 0; t < 2; ++t)
            #pragma unroll
            for (int r = 0; r < 4; ++r) {
                float* p = out + (size_t)(n0 + t * 16 + bq * 4 + r) * 480 + 320 + jc * 5;
                p[0] = o2a[0][t][r]; p[1] = o2a[1][t][r]; p[2] = o2a[2][t][r];
                p[3] = o2a[3][t][r]; p[4] = o2a[4][t][r];
            }
    }
}

extern "C" void kernel_launch(void* const* d_in, const int* in_sizes, int n_in,
                              void* d_out, int out_size, void* d_ws, size_t ws_size,
                              hipStream_t stream)
{
    const float* X   = (const float*)d_in[0];
    const float* Y   = (const float*)d_in[1];
    const float* W0s = (const float*)d_in[2];
    const float* bs  = (const float*)d_in[3];
    const float* W0g = (const float*)d_in[4];
    const float* bg  = (const float*)d_in[5];
    const float* W1  = (const float*)d_in[6];
    const float* W2  = (const float*)d_in[7];
    const float* V0  = (const float*)d_in[8];
    const float* bo  = (const float*)d_in[9];
    const float* V1  = (const float*)d_in[10];
    const float* V2  = (const float*)d_in[11];
    short* WP  = (short*)d_ws;           // 331776 B of bf16-packed weights
    float* out = (float*)d_out;

    const int n = in_sizes[0] / 480;     // 200000
    const int tiles = n / 32;            // 6250 32-node tiles (exact)

    prep_weights<<<dim3((WP_TOTAL + 255) / 256), dim3(256), 0, stream>>>(
        W0s, W0g, W1, W2, V0, V1, V2, WP);
    ffn_main<<<dim3(tiles), dim3(512), 0, stream>>>(X, Y, bs, bg, bo, WP, out);
}

// Round 12
// 328.120 us; speedup vs baseline: 2.3438x; 1.0190x over previous
//
#include <hip/hip_runtime.h>

// ---------------------------------------------------------------------------
// Fused equivariant FFN, bf16 MFMA (16x16x32), fp32 accumulate.
// Round 12 = Round 5/11 anchor (334us) + single theme: eliminate scalar LDS
// accesses.
//  1) gate buffer TRANSPOSED: gT[w][node] stride 36 -> Phase-A writes short4
//     (4 r-consecutive nodes) and B1/B2 epilogues read ds_read_b64, replacing
//     4-way-bank-conflicted scalar u16 traffic (the bulk of the constant
//     1.71e7 SQ_LDS_BANK_CONFLICT).
//  2) x1T staging: 12 scalar b16 writes -> 3 short4 writes.
//  3) x2T staging: 10 scalar b16 writes -> 5 short2 writes.
// Phase structure, barriers, weight prefetch, launch config: byte-identical
// to the anchor (structure rewrites and X-register hoisting are proven
// regressions/miscompiles in this session).
// ---------------------------------------------------------------------------

typedef __attribute__((ext_vector_type(8))) short short8;   // 8 bf16 = 4 VGPRs
typedef __attribute__((ext_vector_type(4))) float f32x4;

#define INV_M0f 0.08838834764831845f   // 1/sqrt(128)
#define INV_M1f 0.125f                 // 1/sqrt(64)
#define INV_M2f 0.17677669529663687f   // 1/sqrt(32)
#define INV_H0f 0.05103103630798288f   // 1/sqrt(384)
#define INV_H1f 0.07216878364870323f   // 1/sqrt(192)
#define INV_H2f 0.10206207261596577f   // 1/sqrt(96)

// packed bf16 weight offsets inside d_ws (units: shorts), pre-scaled by INV_*
#define OFF_W0T 0         // [672][128]  (W0s|W0g)^T * INV_M0
#define OFF_W1T 86016     // [192][64]   W1^T * INV_M1
#define OFF_W2T 98304     // [96][32]    W2^T * INV_M2
#define OFF_V0T 101376    // [128][384]  V0^T * INV_H0
#define OFF_V1T 150528    // [64][192]   V1^T * INV_H1
#define OFF_V2T 162816    // [32][96]    V2^T * INV_H2
#define WP_TOTAL 165888

__device__ __forceinline__ short f2bf_rne(float f) {        // prep only
    union { float f; unsigned u; } v; v.f = f;
    unsigned r = v.u + 0x7FFFu + ((v.u >> 16) & 1u);
    return (short)(r >> 16);
}
// 1-VALU bf16 convert (RNE) for the hot kernel
__device__ __forceinline__ short f2bf_fast(float f) {
    unsigned r;
    asm("v_cvt_pk_bf16_f32 %0, %1, %1" : "=v"(r) : "v"(f));
    return (short)r;
}
__device__ __forceinline__ float bf2f(short s) {
    union { unsigned u; float f; } v; v.u = ((unsigned)(unsigned short)s) << 16;
    return v.f;
}

__global__ void prep_weights(const float* __restrict__ W0s, const float* __restrict__ W0g,
                             const float* __restrict__ W1,  const float* __restrict__ W2,
                             const float* __restrict__ V0,  const float* __restrict__ V1,
                             const float* __restrict__ V2,  short* __restrict__ ws)
{
    int i = blockIdx.x * 256 + threadIdx.x;
    if (i < 86016) {                    // W0T [672][128]
        int j = i >> 7, k = i & 127;
        float v = (j < 384) ? W0s[k * 384 + j] : W0g[k * 288 + (j - 384)];
        ws[i] = f2bf_rne(v * INV_M0f);
    } else if (i < 98304) {             // W1T [192][64]
        int e = i - 86016; int w = e >> 6, u = e & 63;
        ws[i] = f2bf_rne(W1[u * 192 + w] * INV_M1f);
    } else if (i < 101376) {            // W2T [96][32]
        int e = i - 98304; int w = e >> 5, u = e & 31;
        ws[i] = f2bf_rne(W2[u * 96 + w] * INV_M2f);
    } else if (i < 150528) {            // V0T [128][384]
        int e = i - 101376; int j = e / 384, w = e % 384;
        ws[i] = f2bf_rne(V0[w * 128 + j] * INV_H0f);
    } else if (i < 162816) {            // V1T [64][192]
        int e = i - 150528; int j = e / 192, w = e % 192;
        ws[i] = f2bf_rne(V1[w * 64 + j] * INV_H1f);
    } else if (i < WP_TOTAL) {          // V2T [32][96]
        int e = i - 162816; int j = e / 96, w = e % 96;
        ws[i] = f2bf_rne(V2[w * 32 + j] * INV_H2f);
    }
}

// ---- LDS layout (shorts), 32 nodes, total 27264 shorts = 54528 B ----
// x0s  @     0 : [32][136] = 4352   (start -> end Phase A)
// sbuf @  4352 : [32][392] = 12544  (Phase A -> Phase D)    [4352,16896)
// gT   @ 16896 : [288][36] = 10368  (Phase A -> end)        [16896,27264)
//                TRANSPOSED gate: gT[w][node], short4-wide access over nodes
// x1T  @     0 : [3][32][72] = 6912 (after D; overlays dead x0s+sbuf head)
// x2T  @     0 : [5][32][40] = 6400 (after B1; overlays dead x1T)
// ubuf @  6912 : [32][200] = 6400   (B phases; overlays dead sbuf) [6912,13312)
#define X0_STRIDE 136
#define SB_OFF 4352
#define SB_STRIDE 392
#define GT_OFF 16896
#define GT_STRIDE 36
#define UB_OFF 6912
#define UB_STRIDE 200
#define LDS_SHORTS 27264

#define MFMA(a, b, c) __builtin_amdgcn_mfma_f32_16x16x32_bf16((a), (b), (c), 0, 0, 0)

__global__ __launch_bounds__(512, 4) void ffn_main(
    const float* __restrict__ X, const float* __restrict__ Y,
    const float* __restrict__ bs, const float* __restrict__ bg, const float* __restrict__ bo,
    const short* __restrict__ WP, float* __restrict__ out)
{
    __shared__ short lds[LDS_SHORTS];
    short* x0s  = lds;
    short* sbuf = lds + SB_OFF;
    short* gT   = lds + GT_OFF;
    short* x1T  = lds;
    short* x2T  = lds;
    short* ubuf = lds + UB_OFF;

    const int tid  = threadIdx.x;
    const int wid  = tid >> 6;     // wave 0..7
    const int lane = tid & 63;
    const int m    = lane & 15;    // A-row(node) / B-row(out-col) index
    const int bq   = lane >> 4;    // k-block; D row-group
    const int n0   = blockIdx.x * 32;

    // ---- prefetch first Phase-A weight tile (overlaps x0 staging) ----
    short8 w0c[4];
    float bias_c;
    {
        const short* w = WP + OFF_W0T + (wid * 16 + m) * 128 + bq * 8;
        #pragma unroll
        for (int k = 0; k < 4; ++k) w0c[k] = *(const short8*)(w + k * 32);
        bias_c = bs[wid * 16 + m];          // first jt = wid < 24 -> always bs
    }

    // ---- stage x0 (32 nodes x 128 cols) -> LDS bf16, coalesced ----
    {
        const int node = tid >> 4, c16 = tid & 15;
        const float* xp = X + (size_t)(n0 + node) * 480 + c16 * 8;
        float4 f0 = *(const float4*)xp;
        float4 f1 = *(const float4*)(xp + 4);
        short8 a;
        a[0]=f2bf_fast(f0.x); a[1]=f2bf_fast(f0.y); a[2]=f2bf_fast(f0.z); a[3]=f2bf_fast(f0.w);
        a[4]=f2bf_fast(f1.x); a[5]=f2bf_fast(f1.y); a[6]=f2bf_fast(f1.z); a[7]=f2bf_fast(f1.w);
        *(short8*)(x0s + node * X0_STRIDE + c16 * 8) = a;
    }

    // y for the 8 output rows this lane touches: rows t*16 + bq*4 + r
    float yv[2][4];
    #pragma unroll
    for (int t = 0; t < 2; ++t)
        #pragma unroll
        for (int r = 0; r < 4; ++r)
            yv[t][r] = Y[n0 + t * 16 + bq * 4 + r];

    __syncthreads();

    // x0 A-fragments, both row-tiles
    short8 a0[2][4];
    #pragma unroll
    for (int t = 0; t < 2; ++t)
        #pragma unroll
        for (int k = 0; k < 4; ++k)
            a0[t][k] = *(const short8*)(x0s + (t * 16 + m) * X0_STRIDE + k * 32 + bq * 8);

    // ---- Phase A: pre(32x672) = x0 @ W0T^T ; s -> sbuf, g -> gT ----
    // jt = wid + 8i, software-pipelined B-fragments (1 tile ahead)
    #pragma unroll 1
    for (int i = 0; i < 6; ++i) {
        const int jt = wid + i * 8;
        if (jt >= 42) break;
        const int jn = jt + 8;
        short8 w0n[4];
        float bias_n = 0.f;
        if (jn < 42) {
            const short* w = WP + OFF_W0T + (jn * 16 + m) * 128 + bq * 8;
            #pragma unroll
            for (int k = 0; k < 4; ++k) w0n[k] = *(const short8*)(w + k * 32);
            bias_n = (jn < 24) ? bs[jn * 16 + m] : bg[(jn - 24) * 16 + m];
        }
        f32x4 acc0 = {0.f,0.f,0.f,0.f}, acc1 = {0.f,0.f,0.f,0.f};
        #pragma unroll
        for (int k = 0; k < 4; ++k) {
            acc0 = MFMA(a0[0][k], w0c[k], acc0);
            acc1 = MFMA(a0[1][k], w0c[k], acc1);
        }
        if (jt < 24) {          // silu -> sbuf, col j = jt*16+m
            #pragma unroll
            for (int t = 0; t < 2; ++t) {
                f32x4 acc = t ? acc1 : acc0;
                #pragma unroll
                for (int r = 0; r < 4; ++r) {
                    float val = fmaf(acc[r], yv[t][r], bias_c);
                    float e   = __expf(-val);
                    float sv  = val * __builtin_amdgcn_rcpf(1.f + e);
                    sbuf[(t * 16 + bq * 4 + r) * SB_STRIDE + jt * 16 + m] = f2bf_fast(sv);
                }
            }
        } else {                // sigmoid -> gT[w][node], short4 over r
            const int w = (jt - 24) * 16 + m;
            #pragma unroll
            for (int t = 0; t < 2; ++t) {
                f32x4 acc = t ? acc1 : acc0;
                float sg[4];
                #pragma unroll
                for (int r = 0; r < 4; ++r) {
                    float val = fmaf(acc[r], yv[t][r], bias_c);
                    float e   = __expf(-val);
                    sg[r] = __builtin_amdgcn_rcpf(1.f + e);
                }
                short4 pk;
                pk.x = f2bf_fast(sg[0]); pk.y = f2bf_fast(sg[1]);
                pk.z = f2bf_fast(sg[2]); pk.w = f2bf_fast(sg[3]);
                *(short4*)(gT + w * GT_STRIDE + t * 16 + bq * 4) = pk;
            }
        }
        #pragma unroll
        for (int k = 0; k < 4; ++k) w0c[k] = w0n[k];
        bias_c = bias_n;
    }

    // ---- prefetch Phase-D weights (V0T) + bias before the barrier ----
    short8 v0f[12];
    {
        const short* v = WP + OFF_V0T + (wid * 16 + m) * 384 + bq * 8;
        #pragma unroll
        for (int k = 0; k < 12; ++k) v0f[k] = *(const short8*)(v + k * 32);
    }
    const float bo_r = bo[wid * 16 + m];
    __syncthreads();

    // ---- Phase D: o0(32x128) = s @ V0 ; 1 j-tile per wave ----
    {
        f32x4 accD0 = {0.f,0.f,0.f,0.f}, accD1 = {0.f,0.f,0.f,0.f};
        #pragma unroll
        for (int k = 0; k < 12; ++k) {
            short8 sa0 = *(const short8*)(sbuf + m * SB_STRIDE + k * 32 + bq * 8);
            short8 sa1 = *(const short8*)(sbuf + (16 + m) * SB_STRIDE + k * 32 + bq * 8);
            accD0 = MFMA(sa0, v0f[k], accD0);
            accD1 = MFMA(sa1, v0f[k], accD1);
        }
        #pragma unroll
        for (int t = 0; t < 2; ++t) {
            f32x4 acc = t ? accD1 : accD0;
            #pragma unroll
            for (int r = 0; r < 4; ++r)
                out[(size_t)(n0 + t * 16 + bq * 4 + r) * 480 + wid * 16 + m] =
                    fmaf(acc[r], yv[t][r], bo_r);
        }
    }

    // ---- prefetch B1 weights (hoisted across all 3 mm) ----
    short8 w1f[2][2];                   // [jj][k4], jt = wid + jj*8 (<12)
    #pragma unroll
    for (int jj = 0; jj < 2; ++jj) {
        const int jt = wid + jj * 8;
        if (jt < 12) {
            const short* w = WP + OFF_W1T + (jt * 16 + m) * 64 + bq * 8;
            w1f[jj][0] = *(const short8*)(w);
            w1f[jj][1] = *(const short8*)(w + 32);
        }
    }
    short8 v1f[6];                      // waves 4..7: V1T j-tile (wid-4)
    if (wid >= 4) {
        const short* v = WP + OFF_V1T + ((wid - 4) * 16 + m) * 192 + bq * 8;
        #pragma unroll
        for (int k = 0; k < 6; ++k) v1f[k] = *(const short8*)(v + k * 32);
    }
    __syncthreads();   // sbuf now dead; x1T region may be written

    // ---- stage x1 transposed: x1T[mm][node][u]; short4-wide writes ----
    {
        const int node = tid >> 4, c16 = tid & 15;
        const float* xp = X + (size_t)(n0 + node) * 480 + 128 + c16 * 12;
        float4 fa = *(const float4*)xp;
        float4 fb = *(const float4*)(xp + 4);
        float4 fc = *(const float4*)(xp + 8);
        float vals[12] = {fa.x,fa.y,fa.z,fa.w, fb.x,fb.y,fb.z,fb.w, fc.x,fc.y,fc.z,fc.w};
        // col c16*12+c -> (mm = c%3, u = c16*4 + c/3); per mm the 4 values
        // land at consecutive u -> one short4 write each
        #pragma unroll
        for (int mmv = 0; mmv < 3; ++mmv) {
            short4 s4;
            s4.x = f2bf_fast(vals[mmv]);
            s4.y = f2bf_fast(vals[mmv + 3]);
            s4.z = f2bf_fast(vals[mmv + 6]);
            s4.w = f2bf_fast(vals[mmv + 9]);
            *(short4*)(x1T + mmv * 2304 + node * 72 + c16 * 4) = s4;
        }
    }
    __syncthreads();

    // ---- Phase B1: 3 components; GEMM1 (gate) -> ubuf; GEMM2 -> regs ----
    float o1a[3][2][4];                 // waves 4..7 accumulate all mm
    #pragma unroll
    for (int mm = 0; mm < 3; ++mm) {
        // GEMM1: v1_mm(32x192), j-tiles 0..11 (waves 0-3 take 2, 4-7 take 1)
        #pragma unroll
        for (int jj = 0; jj < 2; ++jj) {
            const int jt = wid + jj * 8;
            if (jt < 12) {
                f32x4 accA = {0.f,0.f,0.f,0.f}, accB = {0.f,0.f,0.f,0.f};
                short8 a00 = *(const short8*)(x1T + mm * 2304 + m * 72 + bq * 8);
                short8 a01 = *(const short8*)(x1T + mm * 2304 + m * 72 + 32 + bq * 8);
                short8 a10 = *(const short8*)(x1T + mm * 2304 + (16 + m) * 72 + bq * 8);
                short8 a11 = *(const short8*)(x1T + mm * 2304 + (16 + m) * 72 + 32 + bq * 8);
                accA = MFMA(a00, w1f[jj][0], accA);
                accA = MFMA(a01, w1f[jj][1], accA);
                accB = MFMA(a10, w1f[jj][0], accB);
                accB = MFMA(a11, w1f[jj][1], accB);
                const int w = jt * 16 + m;
                #pragma unroll
                for (int t = 0; t < 2; ++t) {
                    f32x4 acc = t ? accB : accA;
                    short4 g4 = *(const short4*)(gT + w * GT_STRIDE + t * 16 + bq * 4);
                    #pragma unroll
                    for (int r = 0; r < 4; ++r) {
                        const int node = t * 16 + bq * 4 + r;
                        float gv = bf2f(r == 0 ? g4.x : r == 1 ? g4.y : r == 2 ? g4.z : g4.w);
                        ubuf[node * UB_STRIDE + w] =
                            f2bf_fast(acc[r] * yv[t][r] * gv);
                    }
                }
            }
        }
        __syncthreads();
        // GEMM2: o1_mm(32x64) = u @ V1 ; waves 4..7, j-tile (wid-4)
        if (wid >= 4) {
            f32x4 accA = {0.f,0.f,0.f,0.f}, accB = {0.f,0.f,0.f,0.f};
            #pragma unroll
            for (int k = 0; k < 6; ++k) {
                short8 au0 = *(const short8*)(ubuf + m * UB_STRIDE + k * 32 + bq * 8);
                short8 au1 = *(const short8*)(ubuf + (16 + m) * UB_STRIDE + k * 32 + bq * 8);
                accA = MFMA(au0, v1f[k], accA);
                accB = MFMA(au1, v1f[k], accB);
            }
            #pragma unroll
            for (int t = 0; t < 2; ++t) {
                f32x4 acc = t ? accB : accA;
                #pragma unroll
                for (int r = 0; r < 4; ++r)
                    o1a[mm][t][r] = acc[r] * yv[t][r];
            }
        }
        __syncthreads();
    }
    // dense o1 stores: 12B contiguous per lane per row
    if (wid >= 4) {
        const int jc = (wid - 4) * 16 + m;
        #pragma unroll
        for (int t = 0; t < 2; ++t)
            #pragma unroll
            for (int r = 0; r < 4; ++r) {
                float* p = out + (size_t)(n0 + t * 16 + bq * 4 + r) * 480 + 128 + jc * 3;
                p[0] = o1a[0][t][r]; p[1] = o1a[1][t][r]; p[2] = o1a[2][t][r];
            }
    }

    // ---- prefetch B2 weights ----
    short8 w2f;                          // waves 0..5: W2T j-tile wid
    if (wid < 6)
        w2f = *(const short8*)(WP + OFF_W2T + (wid * 16 + m) * 32 + bq * 8);
    short8 v2f[3];                       // waves 6..7: V2T j-tile (wid-6)
    if (wid >= 6) {
        const short* v = WP + OFF_V2T + ((wid - 6) * 16 + m) * 96 + bq * 8;
        #pragma unroll
        for (int k = 0; k < 3; ++k) v2f[k] = *(const short8*)(v + k * 32);
    }

    // ---- stage x2 transposed: x2T[mm][node][u]; short2-wide writes ----
    {
        const int node = tid >> 4, c16 = tid & 15;
        const float* xp = X + (size_t)(n0 + node) * 480 + 320 + c16 * 10;
        float vals[10];
        #pragma unroll
        for (int p = 0; p < 5; ++p) {
            float2 f = *(const float2*)(xp + p * 2);
            vals[p * 2] = f.x; vals[p * 2 + 1] = f.y;
        }
        // col c16*10+c -> (mm = c%5, u = c16*2 + c/5); per mm: 2 consecutive u
        #pragma unroll
        for (int mmv = 0; mmv < 5; ++mmv) {
            short2 s2;
            s2.x = f2bf_fast(vals[mmv]);
            s2.y = f2bf_fast(vals[mmv + 5]);
            *(short2*)(x2T + mmv * 1280 + node * 40 + c16 * 2) = s2;
        }
    }
    __syncthreads();

    // ---- Phase B2: 5 components; GEMM1 (gate) -> ubuf; GEMM2 -> regs ----
    float o2a[5][2][4];                 // waves 6..7
    #pragma unroll
    for (int mm = 0; mm < 5; ++mm) {
        if (wid < 6) {                  // GEMM1: v2_mm(32x96), j-tile wid
            f32x4 accA = {0.f,0.f,0.f,0.f}, accB = {0.f,0.f,0.f,0.f};
            short8 a20 = *(const short8*)(x2T + mm * 1280 + m * 40 + bq * 8);
            short8 a21 = *(const short8*)(x2T + mm * 1280 + (16 + m) * 40 + bq * 8);
            accA = MFMA(a20, w2f, accA);
            accB = MFMA(a21, w2f, accB);
            const int w = 192 + wid * 16 + m;
            #pragma unroll
            for (int t = 0; t < 2; ++t) {
                f32x4 acc = t ? accB : accA;
                short4 g4 = *(const short4*)(gT + w * GT_STRIDE + t * 16 + bq * 4);
                #pragma unroll
                for (int r = 0; r < 4; ++r) {
                    const int node = t * 16 + bq * 4 + r;
                    float gv = bf2f(r == 0 ? g4.x : r == 1 ? g4.y : r == 2 ? g4.z : g4.w);
                    ubuf[node * UB_STRIDE + wid * 16 + m] =
                        f2bf_fast(acc[r] * yv[t][r] * gv);
                }
            }
        }
        __syncthreads();
        if (wid >= 6) {                 // GEMM2: o2_mm(32x32) = u2 @ V2, K=96
            f32x4 accA = {0.f,0.f,0.f,0.f}, accB = {0.f,0.f,0.f,0.f};
            #pragma unroll
            for (int k = 0; k < 3; ++k) {
                short8 au0 = *(const short8*)(ubuf + m * UB_STRIDE + k * 32 + bq * 8);
                short8 au1 = *(const short8*)(ubuf + (16 + m) * UB_STRIDE + k * 32 + bq * 8);
                accA = MFMA(au0, v2f[k], accA);
                accB = MFMA(au1, v2f[k], accB);
            }
            #pragma unroll
            for (int t = 0; t < 2; ++t) {
                f32x4 acc = t ? accB : accA;
                #pragma unroll
                for (int r = 0; r < 4; ++r)
                    o2a[mm][t][r] = acc[r] * yv[t][r];
            }
        }
        if (mm < 4) __syncthreads();
    }
    // dense o2 stores: 20B contiguous per lane per row
    if (wid >= 6) {
        const int jc = (wid - 6) * 16 + m;
        #pragma unroll
        for (int t = 0; t < 2; ++t)
            #pragma unroll
            for (int r = 0; r < 4; ++r) {
                float* p = out + (size_t)(n0 + t * 16 + bq * 4 + r) * 480 + 320 + jc * 5;
                p[0] = o2a[0][t][r]; p[1] = o2a[1][t][r]; p[2] = o2a[2][t][r];
                p[3] = o2a[3][t][r]; p[4] = o2a[4][t][r];
            }
    }
}

extern "C" void kernel_launch(void* const* d_in, const int* in_sizes, int n_in,
                              void* d_out, int out_size, void* d_ws, size_t ws_size,
                              hipStream_t stream)
{
    const float* X   = (const float*)d_in[0];
    const float* Y   = (const float*)d_in[1];
    const float* W0s = (const float*)d_in[2];
    const float* bs  = (const float*)d_in[3];
    const float* W0g = (const float*)d_in[4];
    const float* bg  = (const float*)d_in[5];
    const float* W1  = (const float*)d_in[6];
    const float* W2  = (const float*)d_in[7];
    const float* V0  = (const float*)d_in[8];
    const float* bo  = (const float*)d_in[9];
    const float* V1  = (const float*)d_in[10];
    const float* V2  = (const float*)d_in[11];
    short* WP  = (short*)d_ws;           // 331776 B of bf16-packed weights
    float* out = (float*)d_out;

    const int n = in_sizes[0] / 480;     // 200000
    const int tiles = n / 32;            // 6250 32-node tiles (exact)

    prep_weights<<<dim3((WP_TOTAL + 255) / 256), dim3(256), 0, stream>>>(
        W0s, W0g, W1, W2, V0, V1, V2, WP);
    ffn_main<<<dim3(tiles), dim3(512), 0, stream>>>(X, Y, bs, bg, bo, WP, out);
}